// Round 3
// baseline (167.216 us; speedup 1.0000x reference)
//
#include <hip/hip_runtime.h>
#include <hip/hip_bf16.h>
#include <math.h>

// Sizes fixed by the reference.
#define T_PTS 400
#define D_OUT 10000
#define L12   1200   // len(features1) == len(features2)
#define L3    800    // len(features3)
#define FEAT_TOTAL (L12 + L12 + L3 + 3)   // 3203 floats in d_ws

// ---------------------------------------------------------------------------
// Kernel 1: build the feature vector from input (T,4) into ws:
//   [0,1200)     features1 = [x(400), y(400), z(400)]
//   [1200,2400)  features2 = [jx(400), jy(400), jz(400)]
//   [2400,3200)  features3 = [mags(400), jerk_mags(400)]
//   [3200,3203)  energy (3)
// ---------------------------------------------------------------------------
__global__ __launch_bounds__(512)
void hdc_features_kernel(const float* __restrict__ in, float* __restrict__ feat) {
    __shared__ float red[3][8];
    const int tid = threadIdx.x;          // 0..511
    float ex = 0.f, ey = 0.f, ez = 0.f;

    if (tid < T_PTS) {
        const float4 cur = reinterpret_cast<const float4*>(in)[tid];
        const float x = cur.y, y = cur.z, z = cur.w;
        feat[tid]        = x;
        feat[400 + tid]  = y;
        feat[800 + tid]  = z;
        feat[2400 + tid] = sqrtf(x * x + y * y + z * z);
        ex = x * x; ey = y * y; ez = z * z;

        float jx = 0.f, jy = 0.f, jz = 0.f;
        if (tid > 0) {
            const float4 prev = reinterpret_cast<const float4*>(in)[tid - 1];
            const float dt = cur.x - prev.x;           // t0 offset cancels
            const float inv = 1.0f / dt;
            jx = (x - prev.y) * inv;
            jy = (y - prev.z) * inv;
            jz = (z - prev.w) * inv;
        }
        feat[1200 + tid] = jx;
        feat[1600 + tid] = jy;
        feat[2000 + tid] = jz;
        feat[2800 + tid] = sqrtf(jx * jx + jy * jy + jz * jz);
    }

    // Block-reduce energy sums (wave64 shuffle + LDS across 8 waves).
    #pragma unroll
    for (int off = 32; off; off >>= 1) {
        ex += __shfl_down(ex, off, 64);
        ey += __shfl_down(ey, off, 64);
        ez += __shfl_down(ez, off, 64);
    }
    const int wave = tid >> 6, lane = tid & 63;
    if (lane == 0) { red[0][wave] = ex; red[1][wave] = ey; red[2][wave] = ez; }
    __syncthreads();
    if (tid == 0) {
        float sx = 0.f, sy = 0.f, sz = 0.f;
        #pragma unroll
        for (int w = 0; w < 8; ++w) { sx += red[0][w]; sy += red[1][w]; sz += red[2][w]; }
        const float invT = 1.0f / (float)T_PTS;
        feat[3200] = sx * invT;
        feat[3201] = sy * invT;
        feat[3202] = sz * invT;
    }
}

// ---------------------------------------------------------------------------
// Kernel 2: fused 4-way GEMV + tanh epilogue.
// 1250 blocks x 256 threads (4 waves). Block b owns outputs [8b, 8b+8);
// wave w owns d0 = 8b + 2w, d1 = d0+1. Both rows processed in ONE k-loop
// (4-6 float4 loads in flight per iteration) for memory-level parallelism.
// Whole grid is co-resident (<=8 blocks/CU) so CU load balance is smoothed
// at wave granularity. Features staged in LDS.
// ---------------------------------------------------------------------------
__global__ __launch_bounds__(256)
void hdc_gemv_kernel(const float* __restrict__ W1, const float* __restrict__ b1,
                     const float* __restrict__ W2, const float* __restrict__ b2,
                     const float* __restrict__ W3, const float* __restrict__ b3,
                     const float* __restrict__ W4, const float* __restrict__ b4,
                     const float* __restrict__ feat, float* __restrict__ out) {
    __shared__ float f[FEAT_TOTAL];
    const int tid = threadIdx.x;
    for (int k = tid; k < FEAT_TOTAL; k += 256) f[k] = feat[k];
    __syncthreads();

    const float e0 = f[3200], e1 = f[3201], e2 = f[3202];
    const int wave = tid >> 6, lane = tid & 63;
    const int d0 = blockIdx.x * 8 + wave * 2;   // 1250*8 == 10000, no tail
    const int d1 = d0 + 1;

    const float* __restrict__ f1 = f;
    const float* __restrict__ f2 = f + 1200;
    const float* __restrict__ f3 = f + 2400;

    const float* __restrict__ w1a = W1 + (size_t)d0 * L12;
    const float* __restrict__ w1b = W1 + (size_t)d1 * L12;
    const float* __restrict__ w2a = W2 + (size_t)d0 * L12;
    const float* __restrict__ w2b = W2 + (size_t)d1 * L12;
    const float* __restrict__ w3a = W3 + (size_t)d0 * L3;
    const float* __restrict__ w3b = W3 + (size_t)d1 * L3;

    float a1a = 0.f, a1b = 0.f, a2a = 0.f, a2b = 0.f, a3a = 0.f, a3b = 0.f;

    // L3 segment fused into the first 800 of the L12 loop range:
    for (int k = lane * 4; k < L3; k += 256) {
        const float s1x = f1[k], s1y = f1[k + 1], s1z = f1[k + 2], s1w = f1[k + 3];
        const float s2x = f2[k], s2y = f2[k + 1], s2z = f2[k + 2], s2w = f2[k + 3];
        const float s3x = f3[k], s3y = f3[k + 1], s3z = f3[k + 2], s3w = f3[k + 3];
        const float4 va = *reinterpret_cast<const float4*>(w1a + k);
        const float4 vb = *reinterpret_cast<const float4*>(w1b + k);
        const float4 vc = *reinterpret_cast<const float4*>(w2a + k);
        const float4 vd = *reinterpret_cast<const float4*>(w2b + k);
        const float4 ve = *reinterpret_cast<const float4*>(w3a + k);
        const float4 vf = *reinterpret_cast<const float4*>(w3b + k);
        a1a += va.x * s1x + va.y * s1y + va.z * s1z + va.w * s1w;
        a1b += vb.x * s1x + vb.y * s1y + vb.z * s1z + vb.w * s1w;
        a2a += vc.x * s2x + vc.y * s2y + vc.z * s2z + vc.w * s2w;
        a2b += vd.x * s2x + vd.y * s2y + vd.z * s2z + vd.w * s2w;
        a3a += ve.x * s3x + ve.y * s3y + ve.z * s3z + ve.w * s3w;
        a3b += vf.x * s3x + vf.y * s3y + vf.z * s3z + vf.w * s3w;
    }
    // Remaining [800,1200) of W1/W2 rows:
    for (int k = L3 + lane * 4; k < L12; k += 256) {
        const float s1x = f1[k], s1y = f1[k + 1], s1z = f1[k + 2], s1w = f1[k + 3];
        const float s2x = f2[k], s2y = f2[k + 1], s2z = f2[k + 2], s2w = f2[k + 3];
        const float4 va = *reinterpret_cast<const float4*>(w1a + k);
        const float4 vb = *reinterpret_cast<const float4*>(w1b + k);
        const float4 vc = *reinterpret_cast<const float4*>(w2a + k);
        const float4 vd = *reinterpret_cast<const float4*>(w2b + k);
        a1a += va.x * s1x + va.y * s1y + va.z * s1z + va.w * s1w;
        a1b += vb.x * s1x + vb.y * s1y + vb.z * s1z + vb.w * s1w;
        a2a += vc.x * s2x + vc.y * s2y + vc.z * s2z + vc.w * s2w;
        a2b += vd.x * s2x + vd.y * s2y + vd.z * s2z + vd.w * s2w;
    }

    // wave64 reduction (6 accumulators)
    #pragma unroll
    for (int off = 32; off; off >>= 1) {
        a1a += __shfl_down(a1a, off, 64);
        a1b += __shfl_down(a1b, off, 64);
        a2a += __shfl_down(a2a, off, 64);
        a2b += __shfl_down(a2b, off, 64);
        a3a += __shfl_down(a3a, off, 64);
        a3b += __shfl_down(a3b, off, 64);
    }

    if (lane == 0) {
        const float hv1a = tanhf(a1a + b1[d0]);
        const float hv2a = tanhf(a2a + b2[d0]);
        const float hv3a = tanhf(a3a + b3[d0]);
        const float hv4a = tanhf(W4[(size_t)d0 * 3 + 0] * e0 +
                                 W4[(size_t)d0 * 3 + 1] * e1 +
                                 W4[(size_t)d0 * 3 + 2] * e2 + b4[d0]);
        out[d0] = tanhf(hv1a * hv4a + hv2a + hv3a);

        const float hv1b = tanhf(a1b + b1[d1]);
        const float hv2b = tanhf(a2b + b2[d1]);
        const float hv3b = tanhf(a3b + b3[d1]);
        const float hv4b = tanhf(W4[(size_t)d1 * 3 + 0] * e0 +
                                 W4[(size_t)d1 * 3 + 1] * e1 +
                                 W4[(size_t)d1 * 3 + 2] * e2 + b4[d1]);
        out[d1] = tanhf(hv1b * hv4b + hv2b + hv3b);
    }
}

extern "C" void kernel_launch(void* const* d_in, const int* in_sizes, int n_in,
                              void* d_out, int out_size, void* d_ws, size_t ws_size,
                              hipStream_t stream) {
    const float* input = (const float*)d_in[0];
    const float* W1 = (const float*)d_in[1];
    const float* b1 = (const float*)d_in[2];
    const float* W2 = (const float*)d_in[3];
    const float* b2 = (const float*)d_in[4];
    const float* W3 = (const float*)d_in[5];
    const float* b3 = (const float*)d_in[6];
    const float* W4 = (const float*)d_in[7];
    const float* b4 = (const float*)d_in[8];
    float* out = (float*)d_out;
    float* feat = (float*)d_ws;

    hdc_features_kernel<<<1, 512, 0, stream>>>(input, feat);
    hdc_gemv_kernel<<<D_OUT / 8, 256, 0, stream>>>(W1, b1, W2, b2, W3, b3,
                                                   W4, b4, feat, out);
}